// Round 1
// baseline (1771.223 us; speedup 1.0000x reference)
//
#include <hip/hip_runtime.h>

#define N_NODES 100000
#define IN_DIM 128
#define HID 64
#define OUT_DIM 5
#define N_EDGES 3200000

// ---- degree: cnt[dst] += 1 ----
__global__ __launch_bounds__(256) void degree_k(const int* __restrict__ dst,
                                                float* __restrict__ cnt, int E) {
  int i = blockIdx.x * blockDim.x + threadIdx.x;
  const int stride = gridDim.x * blockDim.x;
  for (int e = i; e < E; e += stride) atomicAdd(&cnt[dst[e]], 1.0f);
}

// ---- fused dual GEMM: Y = X @ Wl^T, Z = X @ Wr^T  (Wl,Wr are [64][K] row-major) ----
// Block = 256 threads = 4 waves; block tile = 64 rows; lane = row, wave = 16-col group.
// Weights read at wave-uniform addresses -> scalar loads (s_load), x via padded LDS.
template <int K>
__global__ __launch_bounds__(256) void gemm_dual(const float* __restrict__ X,
                                                 const float* __restrict__ Wl,
                                                 const float* __restrict__ Wr,
                                                 float* __restrict__ Y,
                                                 float* __restrict__ Z, int n) {
  __shared__ float xT[K * 65];      // [k][row] padded: bank (k+row)%32, conflict-free
  __shared__ float tbuf[64 * 65];   // output transpose staging
  const int t = threadIdx.x;
  const int lane = t & 63;
  const int wv = __builtin_amdgcn_readfirstlane(t >> 6);
  const int colBase = wv * 16;
  const int rowBase = blockIdx.x * 64;

  // stage x tile transposed (coalesced global read)
  for (int i = t; i < 64 * K; i += 256) {
    const int r = i / K, k = i - r * K;
    const int row = rowBase + r;
    xT[k * 65 + r] = (row < n) ? X[(size_t)row * K + k] : 0.0f;
  }
  __syncthreads();

  float accY[16], accZ[16];
#pragma unroll
  for (int j = 0; j < 16; ++j) { accY[j] = 0.0f; accZ[j] = 0.0f; }

  for (int k = 0; k < K; ++k) {
    const float xv = xT[k * 65 + lane];
#pragma unroll
    for (int j = 0; j < 16; ++j) {
      accY[j] = fmaf(xv, Wl[(colBase + j) * K + k], accY[j]);
      accZ[j] = fmaf(xv, Wr[(colBase + j) * K + k], accZ[j]);
    }
  }

  // write Y via LDS transpose (coalesced global stores)
#pragma unroll
  for (int j = 0; j < 16; ++j) tbuf[lane * 65 + colBase + j] = accY[j];
  __syncthreads();
  for (int i = t; i < 64 * 64; i += 256) {
    const int r = i >> 6, c = i & 63;
    if (rowBase + r < n) Y[(size_t)(rowBase + r) * 64 + c] = tbuf[r * 65 + c];
  }
  __syncthreads();
#pragma unroll
  for (int j = 0; j < 16; ++j) tbuf[lane * 65 + colBase + j] = accZ[j];
  __syncthreads();
  for (int i = t; i < 64 * 64; i += 256) {
    const int r = i >> 6, c = i & 63;
    if (rowBase + r < n) Z[(size_t)(rowBase + r) * 64 + c] = tbuf[r * 65 + c];
  }
}

// ---- edge scatter: agg[dst][lane] += Y[src][lane], wave per edge ----
__global__ __launch_bounds__(256) void scatter_k(const int* __restrict__ src,
                                                 const int* __restrict__ dst,
                                                 const float* __restrict__ Y,
                                                 float* __restrict__ agg, int E) {
  const int lane = threadIdx.x & 63;
  const int wid =
      __builtin_amdgcn_readfirstlane((blockIdx.x * blockDim.x + threadIdx.x) >> 6);
  const int nw = (gridDim.x * blockDim.x) >> 6;
  for (int e = wid; e < E; e += nw) {
    const int s = __builtin_amdgcn_readfirstlane(src[e]);
    const int d = __builtin_amdgcn_readfirstlane(dst[e]);
    atomicAdd(&agg[(size_t)d * 64 + lane], Y[(size_t)s * 64 + lane]);
  }
}

// ---- h = relu(agg/max(cnt,1) + bias + z), float4 ----
__global__ __launch_bounds__(256) void combine_relu(const float4* __restrict__ agg,
                                                    const float* __restrict__ cnt,
                                                    const float4* __restrict__ z,
                                                    const float* __restrict__ bias,
                                                    float4* __restrict__ out, int n) {
  int i = blockIdx.x * blockDim.x + threadIdx.x;
  const int stride = gridDim.x * blockDim.x;
  const int tot = n * 16;
  for (; i < tot; i += stride) {
    const int row = i >> 4;
    const int c4 = (i & 15) << 2;
    const float inv = 1.0f / fmaxf(cnt[row], 1.0f);
    const float4 a = agg[i];
    const float4 zv = z[i];
    float4 r;
    r.x = fmaxf(fmaf(a.x, inv, bias[c4 + 0] + zv.x), 0.0f);
    r.y = fmaxf(fmaf(a.y, inv, bias[c4 + 1] + zv.y), 0.0f);
    r.z = fmaxf(fmaf(a.z, inv, bias[c4 + 2] + zv.z), 0.0f);
    r.w = fmaxf(fmaf(a.w, inv, bias[c4 + 3] + zv.w), 0.0f);
    out[i] = r;
  }
}

// ---- final: h2 = relu(agg/cnt + b2l + z); logits = h2 @ Wh^T + bh ----
__global__ __launch_bounds__(256) void final_k(const float* __restrict__ agg,
                                               const float* __restrict__ cnt,
                                               const float* __restrict__ z,
                                               const float* __restrict__ b2l,
                                               const float* __restrict__ Wh,
                                               const float* __restrict__ bh,
                                               float* __restrict__ logits,
                                               float* __restrict__ hout, int n) {
  const int lane = threadIdx.x & 63;
  const int wid = (blockIdx.x * blockDim.x + threadIdx.x) >> 6;
  const int nw = (gridDim.x * blockDim.x) >> 6;
  const float wh0 = Wh[0 * 64 + lane];
  const float wh1 = Wh[1 * 64 + lane];
  const float wh2 = Wh[2 * 64 + lane];
  const float wh3 = Wh[3 * 64 + lane];
  const float wh4 = Wh[4 * 64 + lane];
  const float bl = b2l[lane];
  for (int row = wid; row < n; row += nw) {
    const float inv = 1.0f / fmaxf(cnt[row], 1.0f);
    const float h =
        fmaxf(fmaf(agg[(size_t)row * 64 + lane], inv, bl + z[(size_t)row * 64 + lane]),
              0.0f);
    hout[(size_t)row * 64 + lane] = h;
    float p0 = h * wh0, p1 = h * wh1, p2 = h * wh2, p3 = h * wh3, p4 = h * wh4;
    for (int off = 32; off > 0; off >>= 1) {
      p0 += __shfl_xor(p0, off);
      p1 += __shfl_xor(p1, off);
      p2 += __shfl_xor(p2, off);
      p3 += __shfl_xor(p3, off);
      p4 += __shfl_xor(p4, off);
    }
    if (lane == 0) {
      logits[(size_t)row * 5 + 0] = p0 + bh[0];
      logits[(size_t)row * 5 + 1] = p1 + bh[1];
      logits[(size_t)row * 5 + 2] = p2 + bh[2];
      logits[(size_t)row * 5 + 3] = p3 + bh[3];
      logits[(size_t)row * 5 + 4] = p4 + bh[4];
    }
  }
}

extern "C" void kernel_launch(void* const* d_in, const int* in_sizes, int n_in,
                              void* d_out, int out_size, void* d_ws, size_t ws_size,
                              hipStream_t stream) {
  const float* x = (const float*)d_in[0];
  const int* edge = (const int*)d_in[1];
  const float* W1l = (const float*)d_in[2];
  const float* b1l = (const float*)d_in[3];
  const float* W1r = (const float*)d_in[4];
  const float* W2l = (const float*)d_in[5];
  const float* b2l = (const float*)d_in[6];
  const float* W2r = (const float*)d_in[7];
  const float* Wh = (const float*)d_in[8];
  const float* bh = (const float*)d_in[9];
  const int* src = edge;            // edge_index[0]
  const int* dst = edge + N_EDGES;  // edge_index[1]

  float* out = (float*)d_out;
  float* logits = out;                       // [N,5]
  float* hout = out + (size_t)N_NODES * OUT_DIM;  // [N,64]

  const size_t N64 = (size_t)N_NODES * 64;
  float* y = (float*)d_ws;       // [N,64]
  float* z = y + N64;            // [N,64]
  float* agg = z + N64;          // [N,64]
  float* h1 = agg + N64;         // [N,64]
  float* cnt = h1 + N64;         // [N]

  hipMemsetAsync(agg, 0, N64 * sizeof(float), stream);
  hipMemsetAsync(cnt, 0, N_NODES * sizeof(float), stream);

  degree_k<<<2048, 256, 0, stream>>>(dst, cnt, N_EDGES);

  const int gblocks = (N_NODES + 63) / 64;
  gemm_dual<IN_DIM><<<gblocks, 256, 0, stream>>>(x, W1l, W1r, y, z, N_NODES);
  scatter_k<<<2048, 256, 0, stream>>>(src, dst, y, agg, N_EDGES);
  combine_relu<<<2048, 256, 0, stream>>>((const float4*)agg, cnt, (const float4*)z,
                                         b1l, (float4*)h1, N_NODES);

  gemm_dual<HID><<<gblocks, 256, 0, stream>>>(h1, W2l, W2r, y, z, N_NODES);
  hipMemsetAsync(agg, 0, N64 * sizeof(float), stream);
  scatter_k<<<2048, 256, 0, stream>>>(src, dst, y, agg, N_EDGES);

  final_k<<<2048, 256, 0, stream>>>(agg, cnt, z, b2l, Wh, bh, logits, hout, N_NODES);
}

// Round 2
// 840.235 us; speedup vs baseline: 2.1080x; 2.1080x over previous
//
#include <hip/hip_runtime.h>

#define N_NODES 100000
#define IN_DIM 128
#define HID 64
#define OUT_DIM 5
#define N_EDGES 3200000

#define SCAN_BLK 256
#define SCAN_ELEMS 1024  // 4 per thread
#define SCAN_NB ((N_NODES + SCAN_ELEMS - 1) / SCAN_ELEMS)  // 98

// ---- degree: cnt[dst] += 1 (int atomics) ----
__global__ __launch_bounds__(256) void degree_k(const int* __restrict__ dst,
                                                int* __restrict__ cnt, int E) {
  int i = blockIdx.x * blockDim.x + threadIdx.x;
  const int stride = gridDim.x * blockDim.x;
  for (int e = i; e < E; e += stride) atomicAdd(&cnt[dst[e]], 1);
}

// ---- hierarchical exclusive scan: pass 1 (per-block) ----
__global__ __launch_bounds__(SCAN_BLK) void scan1_k(const int* __restrict__ in,
                                                    int* __restrict__ out,
                                                    int* __restrict__ bsum, int n) {
  __shared__ int tsum[SCAN_BLK];
  const int t = threadIdx.x;
  const int base = blockIdx.x * SCAN_ELEMS + t * 4;
  int v0 = (base + 0 < n) ? in[base + 0] : 0;
  int v1 = (base + 1 < n) ? in[base + 1] : 0;
  int v2 = (base + 2 < n) ? in[base + 2] : 0;
  int v3 = (base + 3 < n) ? in[base + 3] : 0;
  const int s = v0 + v1 + v2 + v3;
  tsum[t] = s;
  __syncthreads();
  // Hillis-Steele inclusive scan over thread sums
  for (int off = 1; off < SCAN_BLK; off <<= 1) {
    int x = (t >= off) ? tsum[t - off] : 0;
    __syncthreads();
    tsum[t] += x;
    __syncthreads();
  }
  const int pre = tsum[t] - s;  // exclusive prefix for this thread
  if (base + 0 < n) out[base + 0] = pre;
  if (base + 1 < n) out[base + 1] = pre + v0;
  if (base + 2 < n) out[base + 2] = pre + v0 + v1;
  if (base + 3 < n) out[base + 3] = pre + v0 + v1 + v2;
  if (t == SCAN_BLK - 1) bsum[blockIdx.x] = tsum[t];
}

// ---- scan pass 2: exclusive scan of block sums (single block) ----
__global__ __launch_bounds__(SCAN_BLK) void scan2_k(int* __restrict__ bsum, int nb) {
  __shared__ int tsum[SCAN_BLK];
  const int t = threadIdx.x;
  const int v = (t < nb) ? bsum[t] : 0;
  tsum[t] = v;
  __syncthreads();
  for (int off = 1; off < SCAN_BLK; off <<= 1) {
    int x = (t >= off) ? tsum[t - off] : 0;
    __syncthreads();
    tsum[t] += x;
    __syncthreads();
  }
  if (t < nb) bsum[t] = tsum[t] - v;
}

// ---- scan pass 3: add block bases; set off[N] ----
__global__ __launch_bounds__(SCAN_BLK) void scan3_k(int* __restrict__ off,
                                                    const int* __restrict__ bsum,
                                                    int n, int total) {
  const int i = blockIdx.x * SCAN_ELEMS + threadIdx.x * 4;
  const int b = bsum[blockIdx.x];
#pragma unroll
  for (int j = 0; j < 4; ++j)
    if (i + j < n) off[i + j] += b;
  if (blockIdx.x == 0 && threadIdx.x == 0) off[n] = total;
}

// ---- counting-sort fill: csr[off[d] + cursor[d]++] = src ----
__global__ __launch_bounds__(256) void fill_k(const int* __restrict__ src,
                                              const int* __restrict__ dst,
                                              const int* __restrict__ off,
                                              int* __restrict__ cursor,
                                              int* __restrict__ csr, int E) {
  int i = blockIdx.x * blockDim.x + threadIdx.x;
  const int stride = gridDim.x * blockDim.x;
  for (int e = i; e < E; e += stride) {
    const int d = dst[e];
    const int pos = off[d] + atomicAdd(&cursor[d], 1);
    csr[pos] = src[e];
  }
}

// ---- fused dual GEMM: Y = X @ Wl^T, Z = X @ Wr^T  (Wl,Wr are [64][K] row-major) ----
template <int K>
__global__ __launch_bounds__(256) void gemm_dual(const float* __restrict__ X,
                                                 const float* __restrict__ Wl,
                                                 const float* __restrict__ Wr,
                                                 float* __restrict__ Y,
                                                 float* __restrict__ Z, int n) {
  __shared__ float xT[K * 65];
  __shared__ float tbuf[64 * 65];
  const int t = threadIdx.x;
  const int lane = t & 63;
  const int wv = __builtin_amdgcn_readfirstlane(t >> 6);
  const int colBase = wv * 16;
  const int rowBase = blockIdx.x * 64;

  for (int i = t; i < 64 * K; i += 256) {
    const int r = i / K, k = i - r * K;
    const int row = rowBase + r;
    xT[k * 65 + r] = (row < n) ? X[(size_t)row * K + k] : 0.0f;
  }
  __syncthreads();

  float accY[16], accZ[16];
#pragma unroll
  for (int j = 0; j < 16; ++j) { accY[j] = 0.0f; accZ[j] = 0.0f; }

  for (int k = 0; k < K; ++k) {
    const float xv = xT[k * 65 + lane];
#pragma unroll
    for (int j = 0; j < 16; ++j) {
      accY[j] = fmaf(xv, Wl[(colBase + j) * K + k], accY[j]);
      accZ[j] = fmaf(xv, Wr[(colBase + j) * K + k], accZ[j]);
    }
  }

#pragma unroll
  for (int j = 0; j < 16; ++j) tbuf[lane * 65 + colBase + j] = accY[j];
  __syncthreads();
  for (int i = t; i < 64 * 64; i += 256) {
    const int r = i >> 6, c = i & 63;
    if (rowBase + r < n) Y[(size_t)(rowBase + r) * 64 + c] = tbuf[r * 65 + c];
  }
  __syncthreads();
#pragma unroll
  for (int j = 0; j < 16; ++j) tbuf[lane * 65 + colBase + j] = accZ[j];
  __syncthreads();
  for (int i = t; i < 64 * 64; i += 256) {
    const int r = i >> 6, c = i & 63;
    if (rowBase + r < n) Z[(size_t)(rowBase + r) * 64 + c] = tbuf[r * 65 + c];
  }
}

// ---- gather-reduce per node + fused epilogue ----
// wave per dst row; lane = channel. h = relu(sum(Y[src])/max(deg,1) + bias + Z[row]).
// FINAL: also logits = h @ Wh^T + bh.
template <bool FINAL>
__global__ __launch_bounds__(256) void gather_k(
    const int* __restrict__ off, const int* __restrict__ csr,
    const float* __restrict__ Y, const float* __restrict__ Z,
    const float* __restrict__ bias, const float* __restrict__ Wh,
    const float* __restrict__ bh, float* __restrict__ H,
    float* __restrict__ logits, int n) {
  const int lane = threadIdx.x & 63;
  const int wid = (blockIdx.x * blockDim.x + threadIdx.x) >> 6;
  const int nw = (gridDim.x * blockDim.x) >> 6;
  float wh0 = 0.f, wh1 = 0.f, wh2 = 0.f, wh3 = 0.f, wh4 = 0.f;
  if (FINAL) {
    wh0 = Wh[0 * 64 + lane];
    wh1 = Wh[1 * 64 + lane];
    wh2 = Wh[2 * 64 + lane];
    wh3 = Wh[3 * 64 + lane];
    wh4 = Wh[4 * 64 + lane];
  }
  const float bl = bias[lane];

  for (int row = wid; row < n; row += nw) {
    const int e0 = off[row];
    const int e1 = off[row + 1];
    float acc0 = 0.0f, acc1 = 0.0f;
    for (int eb = e0; eb < e1; eb += 64) {
      const int m = min(64, e1 - eb);
      const int sidx = (eb + lane < e1) ? csr[eb + lane] : 0;
      int j = 0;
      for (; j + 1 < m; j += 2) {
        const int s0 = __shfl(sidx, j);
        const int s1 = __shfl(sidx, j + 1);
        acc0 += Y[(size_t)s0 * 64 + lane];
        acc1 += Y[(size_t)s1 * 64 + lane];
      }
      if (j < m) {
        const int s0 = __shfl(sidx, j);
        acc0 += Y[(size_t)s0 * 64 + lane];
      }
    }
    const float inv = 1.0f / fmaxf((float)(e1 - e0), 1.0f);
    const float h =
        fmaxf(fmaf(acc0 + acc1, inv, bl + Z[(size_t)row * 64 + lane]), 0.0f);
    H[(size_t)row * 64 + lane] = h;
    if (FINAL) {
      float p0 = h * wh0, p1 = h * wh1, p2 = h * wh2, p3 = h * wh3, p4 = h * wh4;
      for (int o = 32; o > 0; o >>= 1) {
        p0 += __shfl_xor(p0, o);
        p1 += __shfl_xor(p1, o);
        p2 += __shfl_xor(p2, o);
        p3 += __shfl_xor(p3, o);
        p4 += __shfl_xor(p4, o);
      }
      if (lane == 0) {
        logits[(size_t)row * 5 + 0] = p0 + bh[0];
        logits[(size_t)row * 5 + 1] = p1 + bh[1];
        logits[(size_t)row * 5 + 2] = p2 + bh[2];
        logits[(size_t)row * 5 + 3] = p3 + bh[3];
        logits[(size_t)row * 5 + 4] = p4 + bh[4];
      }
    }
  }
}

extern "C" void kernel_launch(void* const* d_in, const int* in_sizes, int n_in,
                              void* d_out, int out_size, void* d_ws, size_t ws_size,
                              hipStream_t stream) {
  const float* x = (const float*)d_in[0];
  const int* edge = (const int*)d_in[1];
  const float* W1l = (const float*)d_in[2];
  const float* b1l = (const float*)d_in[3];
  const float* W1r = (const float*)d_in[4];
  const float* W2l = (const float*)d_in[5];
  const float* b2l = (const float*)d_in[6];
  const float* W2r = (const float*)d_in[7];
  const float* Wh = (const float*)d_in[8];
  const float* bh = (const float*)d_in[9];
  const int* src = edge;
  const int* dst = edge + N_EDGES;

  float* out = (float*)d_out;
  float* logits = out;                            // [N,5]
  float* hout = out + (size_t)N_NODES * OUT_DIM;  // [N,64]

  const size_t N64 = (size_t)N_NODES * 64;
  float* y = (float*)d_ws;  // [N,64]
  float* z = y + N64;       // [N,64]
  float* h1 = z + N64;      // [N,64]
  int* cnt = (int*)(h1 + N64);    // [N]
  int* off = cnt + N_NODES;       // [N+1]
  int* cursor = off + N_NODES + 1;  // [N]
  int* csr = cursor + N_NODES;      // [E]
  int* bsum = csr + N_EDGES;        // [SCAN_NB]

  // ---- CSR build (once; shared by both layers) ----
  hipMemsetAsync(cnt, 0, N_NODES * sizeof(int), stream);
  hipMemsetAsync(cursor, 0, N_NODES * sizeof(int), stream);
  degree_k<<<2048, 256, 0, stream>>>(dst, cnt, N_EDGES);
  scan1_k<<<SCAN_NB, SCAN_BLK, 0, stream>>>(cnt, off, bsum, N_NODES);
  scan2_k<<<1, SCAN_BLK, 0, stream>>>(bsum, SCAN_NB);
  scan3_k<<<SCAN_NB, SCAN_BLK, 0, stream>>>(off, bsum, N_NODES, N_EDGES);
  fill_k<<<2048, 256, 0, stream>>>(src, dst, off, cursor, csr, N_EDGES);

  const int gblocks = (N_NODES + 63) / 64;
  const int wblocks = (N_NODES * 64 + 255) / 256;  // one wave per row

  // ---- layer 1 ----
  gemm_dual<IN_DIM><<<gblocks, 256, 0, stream>>>(x, W1l, W1r, y, z, N_NODES);
  gather_k<false><<<wblocks, 256, 0, stream>>>(off, csr, y, z, b1l, nullptr,
                                               nullptr, h1, nullptr, N_NODES);

  // ---- layer 2 + head ----
  gemm_dual<HID><<<gblocks, 256, 0, stream>>>(h1, W2l, W2r, y, z, N_NODES);
  gather_k<true><<<wblocks, 256, 0, stream>>>(off, csr, y, z, b2l, Wh, bh, hout,
                                              logits, N_NODES);
}